// Round 18
// baseline (828.528 us; speedup 1.0000x reference)
//
#include <hip/hip_runtime.h>
#include <stdint.h>

#define GAS __attribute__((address_space(1)))
#define LAS __attribute__((address_space(3)))

typedef int v4i __attribute__((ext_vector_type(4)));

constexpr int Mdim = 8192;    // B*S = 4*2048
constexpr int Ndim = 16384;   // D_OUT
constexpr int Kdim = 4096;    // D_IN

__device__ __forceinline__ int pack4i8(int a, int b, int c, int d) {
    return (a & 255) | ((b & 255) << 8) | ((c & 255) << 16) | ((d & 255) << 24);
}

__device__ __forceinline__ int qz(float v, float inv) {
    return (int)fminf(fmaxf(rintf(v * inv), -128.0f), 127.0f);
}

// ---- standalone quant kernel (fallback path) ----
__global__ void k_quant_x(const float* __restrict__ x, const float* __restrict__ asc,
                          int8_t* __restrict__ xq) {
    const int i = blockIdx.x * blockDim.x + threadIdx.x;
    const float inv = 1.0f / *asc;
    const float4* xv = (const float4*)x + (size_t)i * 4;
    float4 f0 = xv[0], f1 = xv[1], f2 = xv[2], f3 = xv[3];
    int4 o;
    o.x = pack4i8(qz(f0.x, inv), qz(f0.y, inv), qz(f0.z, inv), qz(f0.w, inv));
    o.y = pack4i8(qz(f1.x, inv), qz(f1.y, inv), qz(f1.z, inv), qz(f1.w, inv));
    o.z = pack4i8(qz(f2.x, inv), qz(f2.y, inv), qz(f2.z, inv), qz(f2.w, inv));
    o.w = pack4i8(qz(f3.x, inv), qz(f3.y, inv), qz(f3.z, inv), qz(f3.w, inv));
    ((int4*)xq)[i] = o;
}

// ---- fused pre-pass: block-ranged quant(x) + conv(w) in one launch ----
constexpr int NQB = (int)((size_t)Mdim * Kdim / 16 / 256);  // 8192
constexpr int NWB = (int)((size_t)Ndim * Kdim / 16 / 256);  // 16384

__global__ void k_prep(const float* __restrict__ x, const int* __restrict__ w,
                       const float* __restrict__ asc,
                       int8_t* __restrict__ xq, int8_t* __restrict__ wq) {
    if (blockIdx.x < NQB) {
        const int i = blockIdx.x * blockDim.x + threadIdx.x;
        const float inv = 1.0f / *asc;
        const float4* xv = (const float4*)x + (size_t)i * 4;
        float4 f0 = xv[0], f1 = xv[1], f2 = xv[2], f3 = xv[3];
        int4 o;
        o.x = pack4i8(qz(f0.x, inv), qz(f0.y, inv), qz(f0.z, inv), qz(f0.w, inv));
        o.y = pack4i8(qz(f1.x, inv), qz(f1.y, inv), qz(f1.z, inv), qz(f1.w, inv));
        o.z = pack4i8(qz(f2.x, inv), qz(f2.y, inv), qz(f2.z, inv), qz(f2.w, inv));
        o.w = pack4i8(qz(f3.x, inv), qz(f3.y, inv), qz(f3.z, inv), qz(f3.w, inv));
        ((int4*)xq)[i] = o;
    } else {
        const int i = (blockIdx.x - NQB) * blockDim.x + threadIdx.x;
        const int4* wv = (const int4*)w + (size_t)i * 4;
        int4 a = wv[0], b = wv[1], c = wv[2], d = wv[3];
        int4 o;
        o.x = pack4i8(a.x, a.y, a.z, a.w);
        o.y = pack4i8(b.x, b.y, b.z, b.w);
        o.z = pack4i8(c.x, c.y, c.z, c.w);
        o.w = pack4i8(d.x, d.y, d.z, d.w);
        ((int4*)wq)[i] = o;
    }
}

// ============================================================================
// pass 2 (main): R10 structure with MERGED PHASES — 4 phases/iter, 32 MFMA
// per barrier (halves barrier+vmcnt count vs R10's 8 phases of 16 MFMA).
// 256x256 tile, 8 waves, K-tile=128B, 2-deep dbuf (128 KiB LDS).
//   merged phase = { 4 B-frag + 8 A-frag ds_read (one full region) ;
//                    stage 1 region (stB+stA = 4 gloads) ; vmcnt(8) ;
//                    s_barrier ; sched_barrier ; setprio(1) 32 MFMA
//                    setprio(0) }
// Stage cadence (iter j, t0=2j, t1=2j+1):
//   ph1 reads b0k0, stages b1k1<-t1   ; ph2 reads b0k1, stages b0k0<-t0+2
//   ph3 reads b1k0, stages b0k1<-t0+2; ph4 reads b1k1, stages b1k0<-t1+2
// Ledger (verified): outstanding at every vmcnt = 12-16 loads; vmcnt(8)
// retires exactly the region whose reads issue next phase (>=1 barrier
// later). Write-hazard: each stage targets a region whose last reads were
// lgkm-drained before the previous phase's MFMA (>=1 barrier upstream) —
// same pattern R10/R15 validated. Tail iter: stages ph1 only; peel
// vmcnt(8)/(4)/(0). Swizzle identical (verified 0 bank conflicts).
// NON-TEMPORAL C stores kept from R15.
// ============================================================================
constexpr int NT    = Kdim / 128;  // 32 K-tiles
constexpr int NITER = NT / 2;      // 16

#define VM8  asm volatile("s_waitcnt vmcnt(8)"  ::: "memory")
#define VM4  asm volatile("s_waitcnt vmcnt(4)"  ::: "memory")
#define VM0  asm volatile("s_waitcnt vmcnt(0)"  ::: "memory")

#define MPH(ABASE, STG1, STG2, VM_STMT)                                        \
  {                                                                            \
    _Pragma("unroll") for (int f = 0; f < 4; ++f)                              \
        bfr[f] = *(const v4i*)(lds + (ABASE) + 32768 + browb + f * 1024);      \
    _Pragma("unroll") for (int f = 0; f < 8; ++f)                              \
        afr[f] = *(const v4i*)(lds + (ABASE) + arow0 + f * 1024);              \
    STG1;                                                                      \
    STG2;                                                                      \
    VM_STMT;                                                                   \
    __builtin_amdgcn_s_barrier();                                              \
    __builtin_amdgcn_sched_barrier(0);                                         \
    __builtin_amdgcn_s_setprio(1);                                             \
    _Pragma("unroll") for (int fi = 0; fi < 8; ++fi)                           \
        _Pragma("unroll") for (int fj = 0; fj < 4; ++fj)                       \
            acc[fi][fj] = __builtin_amdgcn_mfma_i32_16x16x64_i8(               \
                afr[fi], bfr[fj], acc[fi][fj], 0, 0, 0);                       \
    __builtin_amdgcn_s_setprio(0);                                             \
  }

__global__ __launch_bounds__(512, 2)
void k_gemm256(const int8_t* __restrict__ Aq, const int8_t* __restrict__ Bq,
               const float* __restrict__ wscale, const float* __restrict__ asc,
               const float* __restrict__ bias, float* __restrict__ out) {
    __shared__ __align__(16) int8_t lds[131072];
    const int tid = threadIdx.x, lane = tid & 63, w = tid >> 6;
    const int wm = w >> 2, wn = w & 3;              // 2M x 4N wave grid
    const int lrow = lane & 15, kgrp = lane >> 4;

    const int bid = blockIdx.x;                     // grid = 2048, %8 == 0
    const int swz = ((bid & 7) << 8) | (bid >> 3);  // bijective XCD swizzle
    const int mt = swz & 31, nt = swz >> 5;         // m fastest: share B panel
    const int m0 = mt << 8, n0 = nt << 8;

    // ---- staging geometry (verified 0-conflict, rounds 2-17) ----
    const int srow = tid >> 2;                      // row within 128-row unit
    const int scol = (((tid & 3) ^ ((tid >> 3) & 3)) << 4);
    const int8_t* rowA0 = Aq + (size_t)(m0 + srow) * Kdim + scol;
    const int8_t* rowB0 = Bq + (size_t)(n0 + srow) * Kdim + scol;
    const size_t rb1off = (size_t)128 * Kdim;
    const int dstoff = w << 10;                     // + HW lane*16

    auto stA = [&](int t, int ks) {
        int8_t* d = lds + ((t & 1) << 16) + (ks << 14) + dstoff;
        const int8_t* s = rowA0 + t * 128 + ks * 64;
        __builtin_amdgcn_global_load_lds((const GAS void*)s, (LAS void*)d, 16, 0, 0);
        __builtin_amdgcn_global_load_lds((const GAS void*)(s + rb1off), (LAS void*)(d + 8192), 16, 0, 0);
    };
    auto stB = [&](int t, int ks) {
        int8_t* d = lds + ((t & 1) << 16) + 32768 + (ks << 14) + dstoff;
        const int8_t* s = rowB0 + t * 128 + ks * 64;
        __builtin_amdgcn_global_load_lds((const GAS void*)s, (LAS void*)d, 16, 0, 0);
        __builtin_amdgcn_global_load_lds((const GAS void*)(s + rb1off), (LAS void*)(d + 8192), 16, 0, 0);
    };

    // ---- read-side addressing (verified conflict-free swizzle) ----
    const int kc = (kgrp ^ ((lrow >> 1) & 3)) << 4;
    const int arow0 = ((wm << 7) + lrow) * 64 + kc;   // f*1024 spans all 128 rows
    const int browb = ((wn << 6) + lrow) * 64 + kc;

    v4i acc[8][4];
#pragma unroll
    for (int i = 0; i < 8; ++i)
#pragma unroll
        for (int j = 0; j < 4; ++j) acc[i][j] = (v4i){0, 0, 0, 0};

    v4i afr[8], bfr[4];

    // prologue: stage regions b0k0, b0k1, b1k0 (12 loads); drain; barrier.
    stB(0, 0); stA(0, 0); stB(0, 1); stA(0, 1); stB(1, 0); stA(1, 0);
    VM0;
    __builtin_amdgcn_s_barrier();

    for (int j = 0; j < NITER - 1; ++j) {
        const int t0 = 2 * j, t1 = 2 * j + 1;
        MPH(0,     stB(t1, 1),     stA(t1, 1),     VM8)   // ph1: b0k0
        MPH(16384, stB(t0 + 2, 0), stA(t0 + 2, 0), VM8)   // ph2: b0k1
        MPH(65536, stB(t0 + 2, 1), stA(t0 + 2, 1), VM8)   // ph3: b1k0
        MPH(81920, stB(t1 + 2, 0), stA(t1 + 2, 0), VM8)   // ph4: b1k1
    }

    // tail iter (tiles 30,31): stages ph1 only; vmcnt peels 8/4/0.
    {
        MPH(0,     stB(31, 1), stA(31, 1), VM8)           // ph1: b0k0
        MPH(16384, (void)0,    (void)0,    VM4)           // ph2: b0k1
        MPH(65536, (void)0,    (void)0,    VM0)           // ph3: b1k0
        MPH(81920, (void)0,    (void)0,    (void)0)       // ph4: b1k1
    }

    // epilogue: y = i32 * (act_scale * wscale[n]) + bias[n]
    const float ascale = *asc;
#pragma unroll
    for (int fj = 0; fj < 4; ++fj) {
        const int col = n0 + (wn << 6) + fj * 16 + lrow;
        const float sc = ascale * wscale[col];
        const float bb = bias[col];
#pragma unroll
        for (int mi = 0; mi < 8; ++mi) {
            const int r0 = m0 + (wm << 7) + mi * 16 + (kgrp << 2);
            float* o = out + (size_t)r0 * Ndim + col;
#pragma unroll
            for (int q = 0; q < 4; ++q)
                __builtin_nontemporal_store((float)acc[mi][fj][q] * sc + bb,
                                            o + (size_t)q * Ndim);
        }
    }
}

// ============================================================================
// fallback 128x128 kernel (only used if workspace is too small)
// ============================================================================
template <bool AQ, bool BQ>
__global__ __launch_bounds__(256)
void k_gemm(const int8_t* __restrict__ Aq, const float* __restrict__ Xf,
            const int8_t* __restrict__ Bq, const int* __restrict__ W32,
            const float* __restrict__ wscale, const float* __restrict__ asc,
            const float* __restrict__ bias, float* __restrict__ out) {
    constexpr int BM = 128, BN = 128, BK = 64;
    constexpr int KT = Kdim / BK;
    __shared__ __align__(16) int8_t As[2][BM * BK];
    __shared__ __align__(16) int8_t Bs[2][BN * BK];

    const int tid  = threadIdx.x;
    const int lane = tid & 63;
    const int wid  = tid >> 6;
    const int wm = wid >> 1, wn = wid & 1;
    const int lrow = lane & 15, kgrp = lane >> 4;

    const int cpx = gridDim.x >> 3;
    const int swz = ((int)blockIdx.x & 7) * cpx + ((int)blockIdx.x >> 3);
    const int mt = swz & (Mdim / BM - 1);
    const int nt = swz / (Mdim / BM);
    const int m0 = mt * BM, n0 = nt * BN;

    const float ascale = *asc;
    const float inv = 1.0f / ascale;

    v4i acc[4][4];
#pragma unroll
    for (int i = 0; i < 4; ++i)
#pragma unroll
        for (int j = 0; j < 4; ++j) acc[i][j] = (v4i){0, 0, 0, 0};

    auto stage = [&](int buf, int kt) {
        const int k0 = kt * BK;
        if constexpr (AQ) {
            int8_t* ldsp = &As[buf][wid << 10];
            const int8_t* g = Aq + (size_t)(m0 + (tid >> 2)) * Kdim + k0 + ((tid & 3) << 4);
            __builtin_amdgcn_global_load_lds((const GAS void*)g, (LAS void*)ldsp, 16, 0, 0);
            __builtin_amdgcn_global_load_lds((const GAS void*)(g + (size_t)64 * Kdim),
                                             (LAS void*)(ldsp + 4096), 16, 0, 0);
        } else {
            const int row = tid >> 1, cb = (tid & 1) << 5;
            const float4* src = (const float4*)(Xf + (size_t)(m0 + row) * Kdim + k0 + cb);
            int t[8];
#pragma unroll
            for (int j = 0; j < 8; ++j) {
                float4 f = src[j];
                t[j] = pack4i8(qz(f.x, inv), qz(f.y, inv), qz(f.z, inv), qz(f.w, inv));
            }
            int4* dst = (int4*)&As[buf][row * BK + cb];
            dst[0] = make_int4(t[0], t[1], t[2], t[3]);
            dst[1] = make_int4(t[4], t[5], t[6], t[7]);
        }
        if constexpr (BQ) {
            int8_t* ldsp = &Bs[buf][wid << 10];
            const int8_t* g = Bq + (size_t)(n0 + (tid >> 2)) * Kdim + k0 + ((tid & 3) << 4);
            __builtin_amdgcn_global_load_lds((const GAS void*)g, (LAS void*)ldsp, 16, 0, 0);
            __builtin_amdgcn_global_load_lds((const GAS void*)(g + (size_t)64 * Kdim),
                                             (LAS void*)(ldsp + 4096), 16, 0, 0);
        } else {
            const int row = tid >> 1, cb = (tid & 1) << 5;
            const int4* src = (const int4*)(W32 + (size_t)(n0 + row) * Kdim + k0 + cb);
            int t[8];
#pragma unroll
            for (int j = 0; j < 8; ++j) {
                int4 vv = src[j];
                t[j] = pack4i8(vv.x, vv.y, vv.z, vv.w);
            }
            int4* dst = (int4*)&Bs[buf][row * BK + cb];
            dst[0] = make_int4(t[0], t[1], t[2], t[3]);
            dst[1] = make_int4(t[4], t[5], t[6], t[7]);
        }
    };

    stage(0, 0);
    for (int kt = 0; kt < KT; ++kt) {
        const int cur = kt & 1;
        __syncthreads();
        if (kt + 1 < KT) stage(cur ^ 1, kt + 1);

        v4i a[4], b[4];
        const int koff = kgrp << 4;
#pragma unroll
        for (int i = 0; i < 4; ++i) {
            a[i] = *(const v4i*)&As[cur][(wm * 64 + i * 16 + lrow) * BK + koff];
            b[i] = *(const v4i*)&Bs[cur][(wn * 64 + i * 16 + lrow) * BK + koff];
        }
#pragma unroll
        for (int i = 0; i < 4; ++i)
#pragma unroll
            for (int j = 0; j < 4; ++j)
                acc[i][j] = __builtin_amdgcn_mfma_i32_16x16x64_i8(a[i], b[j], acc[i][j], 0, 0, 0);
    }

#pragma unroll
    for (int j = 0; j < 4; ++j) {
        const int col = n0 + wn * 64 + j * 16 + lrow;
        const float sc = ascale * wscale[col];
        const float bb = bias[col];
#pragma unroll
        for (int i = 0; i < 4; ++i) {
            const int r0 = m0 + wm * 64 + i * 16 + (kgrp << 2);
            float* o = out + (size_t)r0 * Ndim + col;
#pragma unroll
            for (int r = 0; r < 4; ++r)
                o[(size_t)r * Ndim] = (float)acc[i][j][r] * sc + bb;
        }
    }
}

extern "C" void kernel_launch(void* const* d_in, const int* in_sizes, int n_in,
                              void* d_out, int out_size, void* d_ws, size_t ws_size,
                              hipStream_t stream) {
    const float* x      = (const float*)d_in[0];
    const int*   w32    = (const int*)d_in[1];   // int8 values sign-extended to int32
    const float* wscale = (const float*)d_in[2];
    const float* asc    = (const float*)d_in[3];
    const float* bias   = (const float*)d_in[4];
    float* out = (float*)d_out;

    const size_t nx = (size_t)Mdim * Kdim;  // 33,554,432 B for x_int8
    const size_t nw = (size_t)Ndim * Kdim;  // 67,108,864 B for w_int8
    int8_t* xq = (int8_t*)d_ws;
    int8_t* wq = xq + nx;

    const bool haveX = ws_size >= nx;
    const bool haveW = ws_size >= nx + nw;

    if (haveW) {
        k_prep<<<NQB + NWB, 256, 0, stream>>>(x, w32, asc, xq, wq);
        dim3 grid((Mdim / 256) * (Ndim / 256));  // 2048
        k_gemm256<<<grid, 512, 0, stream>>>(xq, wq, wscale, asc, bias, out);
    } else if (haveX) {
        k_quant_x<<<NQB, 256, 0, stream>>>(x, asc, xq);
        dim3 grid((Mdim / 128) * (Ndim / 128));  // 8192
        k_gemm<true, false><<<grid, 256, 0, stream>>>(xq, x, wq, w32, wscale, asc, bias, out);
    } else {
        dim3 grid((Mdim / 128) * (Ndim / 128));
        k_gemm<false, false><<<grid, 256, 0, stream>>>(xq, x, wq, w32, wscale, asc, bias, out);
    }
}

// Round 19
// 777.802 us; speedup vs baseline: 1.0652x; 1.0652x over previous
//
#include <hip/hip_runtime.h>
#include <stdint.h>

#define GAS __attribute__((address_space(1)))
#define LAS __attribute__((address_space(3)))

typedef int v4i __attribute__((ext_vector_type(4)));

constexpr int Mdim = 8192;    // B*S = 4*2048
constexpr int Ndim = 16384;   // D_OUT
constexpr int Kdim = 4096;    // D_IN

__device__ __forceinline__ int pack4i8(int a, int b, int c, int d) {
    return (a & 255) | ((b & 255) << 8) | ((c & 255) << 16) | ((d & 255) << 24);
}

__device__ __forceinline__ int qz(float v, float inv) {
    return (int)fminf(fmaxf(rintf(v * inv), -128.0f), 127.0f);
}

// ---- standalone quant kernel (fallback path) ----
__global__ void k_quant_x(const float* __restrict__ x, const float* __restrict__ asc,
                          int8_t* __restrict__ xq) {
    const int i = blockIdx.x * blockDim.x + threadIdx.x;
    const float inv = 1.0f / *asc;
    const float4* xv = (const float4*)x + (size_t)i * 4;
    float4 f0 = xv[0], f1 = xv[1], f2 = xv[2], f3 = xv[3];
    int4 o;
    o.x = pack4i8(qz(f0.x, inv), qz(f0.y, inv), qz(f0.z, inv), qz(f0.w, inv));
    o.y = pack4i8(qz(f1.x, inv), qz(f1.y, inv), qz(f1.z, inv), qz(f1.w, inv));
    o.z = pack4i8(qz(f2.x, inv), qz(f2.y, inv), qz(f2.z, inv), qz(f2.w, inv));
    o.w = pack4i8(qz(f3.x, inv), qz(f3.y, inv), qz(f3.z, inv), qz(f3.w, inv));
    ((int4*)xq)[i] = o;
}

// ---- fused pre-pass: block-ranged quant(x) + conv(w) in one launch ----
constexpr int NQB = (int)((size_t)Mdim * Kdim / 16 / 256);  // 8192
constexpr int NWB = (int)((size_t)Ndim * Kdim / 16 / 256);  // 16384

__global__ void k_prep(const float* __restrict__ x, const int* __restrict__ w,
                       const float* __restrict__ asc,
                       int8_t* __restrict__ xq, int8_t* __restrict__ wq) {
    if (blockIdx.x < NQB) {
        const int i = blockIdx.x * blockDim.x + threadIdx.x;
        const float inv = 1.0f / *asc;
        const float4* xv = (const float4*)x + (size_t)i * 4;
        float4 f0 = xv[0], f1 = xv[1], f2 = xv[2], f3 = xv[3];
        int4 o;
        o.x = pack4i8(qz(f0.x, inv), qz(f0.y, inv), qz(f0.z, inv), qz(f0.w, inv));
        o.y = pack4i8(qz(f1.x, inv), qz(f1.y, inv), qz(f1.z, inv), qz(f1.w, inv));
        o.z = pack4i8(qz(f2.x, inv), qz(f2.y, inv), qz(f2.z, inv), qz(f2.w, inv));
        o.w = pack4i8(qz(f3.x, inv), qz(f3.y, inv), qz(f3.z, inv), qz(f3.w, inv));
        ((int4*)xq)[i] = o;
    } else {
        const int i = (blockIdx.x - NQB) * blockDim.x + threadIdx.x;
        const int4* wv = (const int4*)w + (size_t)i * 4;
        int4 a = wv[0], b = wv[1], c = wv[2], d = wv[3];
        int4 o;
        o.x = pack4i8(a.x, a.y, a.z, a.w);
        o.y = pack4i8(b.x, b.y, b.z, b.w);
        o.z = pack4i8(c.x, c.y, c.z, c.w);
        o.w = pack4i8(d.x, d.y, d.z, d.w);
        ((int4*)wq)[i] = o;
    }
}

// ============================================================================
// pass 2 (main): round-10 structure — best measured across 16 structural
// variants (687 us GEMM). 256x256, 8 waves, K-tile=128B, 2-deep dbuf
// (128 KiB LDS), 8 phases/iter, ONE barrier per phase:
//   phase p = { ds_read frags(p) ; stage 1 region ; vmcnt(8) ; s_barrier ;
//               sched_barrier ; setprio(1) 16 MFMA setprio(0) }
// The 8-phase granularity is load-bearing (R18: merging to 4 phases of 32
// MFMA regressed 687->870 — coarse phases expose the full read-drain per
// barrier; fine phases let counted-lgkm interleave hide it).
// NON-TEMPORAL C stores (measured neutral, kept). Hazard ledger verified
// rounds 10/15/17 (passed, 0 bank conflicts).
// ============================================================================
constexpr int NT    = Kdim / 128;  // 32 K-tiles
constexpr int NITER = NT / 2;      // 16

#define VM8  asm volatile("s_waitcnt vmcnt(8)"  ::: "memory")
#define VM4  asm volatile("s_waitcnt vmcnt(4)"  ::: "memory")
#define VM0  asm volatile("s_waitcnt vmcnt(0)"  ::: "memory")

#define PH(ABASE, READB, AROW, ACC0, STAGE_STMT, VM_STMT)                      \
  {                                                                            \
    if (READB) {                                                               \
      _Pragma("unroll") for (int f = 0; f < 4; ++f)                            \
          bfr[f] = *(const v4i*)(lds + (ABASE) + 32768 + browb + f * 1024);    \
    }                                                                          \
    _Pragma("unroll") for (int f = 0; f < 4; ++f)                              \
        afr[f] = *(const v4i*)(lds + (ABASE) + (AROW) + f * 1024);             \
    STAGE_STMT;                                                                \
    VM_STMT;                                                                   \
    __builtin_amdgcn_s_barrier();                                              \
    __builtin_amdgcn_sched_barrier(0);                                         \
    __builtin_amdgcn_s_setprio(1);                                             \
    _Pragma("unroll") for (int fi = 0; fi < 4; ++fi)                           \
        _Pragma("unroll") for (int fj = 0; fj < 4; ++fj)                       \
            acc[(ACC0) + fi][fj] = __builtin_amdgcn_mfma_i32_16x16x64_i8(      \
                afr[fi], bfr[fj], acc[(ACC0) + fi][fj], 0, 0, 0);              \
    __builtin_amdgcn_s_setprio(0);                                             \
  }

__global__ __launch_bounds__(512, 2)
void k_gemm256(const int8_t* __restrict__ Aq, const int8_t* __restrict__ Bq,
               const float* __restrict__ wscale, const float* __restrict__ asc,
               const float* __restrict__ bias, float* __restrict__ out) {
    __shared__ __align__(16) int8_t lds[131072];
    const int tid = threadIdx.x, lane = tid & 63, w = tid >> 6;
    const int wm = w >> 2, wn = w & 3;              // 2M x 4N wave grid
    const int lrow = lane & 15, kgrp = lane >> 4;

    const int bid = blockIdx.x;                     // grid = 2048, %8 == 0
    const int swz = ((bid & 7) << 8) | (bid >> 3);  // bijective XCD swizzle
    const int mt = swz & 31, nt = swz >> 5;         // m fastest: share B panel
    const int m0 = mt << 8, n0 = nt << 8;

    // ---- staging geometry (verified 0-conflict, rounds 2-17) ----
    const int srow = tid >> 2;                      // row within 128-row unit
    const int scol = (((tid & 3) ^ ((tid >> 3) & 3)) << 4);
    const int8_t* rowA0 = Aq + (size_t)(m0 + srow) * Kdim + scol;
    const int8_t* rowB0 = Bq + (size_t)(n0 + srow) * Kdim + scol;
    const size_t rb1off = (size_t)128 * Kdim;
    const int dstoff = w << 10;                     // + HW lane*16

    auto stA = [&](int t, int ks) {
        int8_t* d = lds + ((t & 1) << 16) + (ks << 14) + dstoff;
        const int8_t* s = rowA0 + t * 128 + ks * 64;
        __builtin_amdgcn_global_load_lds((const GAS void*)s, (LAS void*)d, 16, 0, 0);
        __builtin_amdgcn_global_load_lds((const GAS void*)(s + rb1off), (LAS void*)(d + 8192), 16, 0, 0);
    };
    auto stB = [&](int t, int ks) {
        int8_t* d = lds + ((t & 1) << 16) + 32768 + (ks << 14) + dstoff;
        const int8_t* s = rowB0 + t * 128 + ks * 64;
        __builtin_amdgcn_global_load_lds((const GAS void*)s, (LAS void*)d, 16, 0, 0);
        __builtin_amdgcn_global_load_lds((const GAS void*)(s + rb1off), (LAS void*)(d + 8192), 16, 0, 0);
    };

    // ---- read-side addressing (verified conflict-free swizzle) ----
    const int kc = (kgrp ^ ((lrow >> 1) & 3)) << 4;
    const int arow0 = ((wm << 7) + lrow) * 64 + kc;        // h0 rows
    const int arow1 = ((wm << 7) + 64 + lrow) * 64 + kc;   // h1 rows
    const int browb = ((wn << 6) + lrow) * 64 + kc;

    v4i acc[8][4];
#pragma unroll
    for (int i = 0; i < 8; ++i)
#pragma unroll
        for (int j = 0; j < 4; ++j) acc[i][j] = (v4i){0, 0, 0, 0};

    v4i afr[4], bfr[4];

    // prologue: stage (b0k0),(b0k1),(b1k0) A+B = 12 loads; drain; barrier.
    stB(0, 0); stA(0, 0); stB(0, 1); stA(0, 1); stB(1, 0); stA(1, 0);
    VM0;
    __builtin_amdgcn_s_barrier();

    for (int j = 0; j < NITER - 1; ++j) {
        const int t0 = 2 * j, t1 = 2 * j + 1;
        PH(0,     true,  arow0, 0, stB(t1, 1),     VM8)   // ph1
        PH(0,     false, arow1, 4, stA(t1, 1),     VM8)   // ph2
        PH(16384, true,  arow0, 0, stB(t0 + 2, 0), VM8)   // ph3
        PH(16384, false, arow1, 4, stA(t0 + 2, 0), VM8)   // ph4
        PH(65536, true,  arow0, 0, stB(t0 + 2, 1), VM8)   // ph5
        PH(65536, false, arow1, 4, stA(t0 + 2, 1), VM8)   // ph6
        PH(81920, true,  arow0, 0, stB(t1 + 2, 0), VM8)   // ph7
        PH(81920, false, arow1, 4, stA(t1 + 2, 0), VM8)   // ph8
    }

    // tail iter (tiles 30,31): stages ph1/ph2 only; vmcnt peels 4/0.
    {
        PH(0,     true,  arow0, 0, stB(31, 1), VM8)       // ph1
        PH(0,     false, arow1, 4, stA(31, 1), VM8)       // ph2
        PH(16384, true,  arow0, 0, (void)0,    (void)0)   // ph3
        PH(16384, false, arow1, 4, (void)0,    VM4)       // ph4
        PH(65536, true,  arow0, 0, (void)0,    (void)0)   // ph5
        PH(65536, false, arow1, 4, (void)0,    VM0)       // ph6
        PH(81920, true,  arow0, 0, (void)0,    (void)0)   // ph7
        PH(81920, false, arow1, 4, (void)0,    (void)0)   // ph8
    }

    // epilogue: y = i32 * (act_scale * wscale[n]) + bias[n]
    const float ascale = *asc;
#pragma unroll
    for (int fj = 0; fj < 4; ++fj) {
        const int col = n0 + (wn << 6) + fj * 16 + lrow;
        const float sc = ascale * wscale[col];
        const float bb = bias[col];
#pragma unroll
        for (int mi = 0; mi < 8; ++mi) {
            const int r0 = m0 + (wm << 7) + mi * 16 + (kgrp << 2);
            float* o = out + (size_t)r0 * Ndim + col;
#pragma unroll
            for (int q = 0; q < 4; ++q)
                __builtin_nontemporal_store((float)acc[mi][fj][q] * sc + bb,
                                            o + (size_t)q * Ndim);
        }
    }
}

// ============================================================================
// fallback 128x128 kernel (only used if workspace is too small)
// ============================================================================
template <bool AQ, bool BQ>
__global__ __launch_bounds__(256)
void k_gemm(const int8_t* __restrict__ Aq, const float* __restrict__ Xf,
            const int8_t* __restrict__ Bq, const int* __restrict__ W32,
            const float* __restrict__ wscale, const float* __restrict__ asc,
            const float* __restrict__ bias, float* __restrict__ out) {
    constexpr int BM = 128, BN = 128, BK = 64;
    constexpr int KT = Kdim / BK;
    __shared__ __align__(16) int8_t As[2][BM * BK];
    __shared__ __align__(16) int8_t Bs[2][BN * BK];

    const int tid  = threadIdx.x;
    const int lane = tid & 63;
    const int wid  = tid >> 6;
    const int wm = wid >> 1, wn = wid & 1;
    const int lrow = lane & 15, kgrp = lane >> 4;

    const int cpx = gridDim.x >> 3;
    const int swz = ((int)blockIdx.x & 7) * cpx + ((int)blockIdx.x >> 3);
    const int mt = swz & (Mdim / BM - 1);
    const int nt = swz / (Mdim / BM);
    const int m0 = mt * BM, n0 = nt * BN;

    const float ascale = *asc;
    const float inv = 1.0f / ascale;

    v4i acc[4][4];
#pragma unroll
    for (int i = 0; i < 4; ++i)
#pragma unroll
        for (int j = 0; j < 4; ++j) acc[i][j] = (v4i){0, 0, 0, 0};

    auto stage = [&](int buf, int kt) {
        const int k0 = kt * BK;
        if constexpr (AQ) {
            int8_t* ldsp = &As[buf][wid << 10];
            const int8_t* g = Aq + (size_t)(m0 + (tid >> 2)) * Kdim + k0 + ((tid & 3) << 4);
            __builtin_amdgcn_global_load_lds((const GAS void*)g, (LAS void*)ldsp, 16, 0, 0);
            __builtin_amdgcn_global_load_lds((const GAS void*)(g + (size_t)64 * Kdim),
                                             (LAS void*)(ldsp + 4096), 16, 0, 0);
        } else {
            const int row = tid >> 1, cb = (tid & 1) << 5;
            const float4* src = (const float4*)(Xf + (size_t)(m0 + row) * Kdim + k0 + cb);
            int t[8];
#pragma unroll
            for (int j = 0; j < 8; ++j) {
                float4 f = src[j];
                t[j] = pack4i8(qz(f.x, inv), qz(f.y, inv), qz(f.z, inv), qz(f.w, inv));
            }
            int4* dst = (int4*)&As[buf][row * BK + cb];
            dst[0] = make_int4(t[0], t[1], t[2], t[3]);
            dst[1] = make_int4(t[4], t[5], t[6], t[7]);
        }
        if constexpr (BQ) {
            int8_t* ldsp = &Bs[buf][wid << 10];
            const int8_t* g = Bq + (size_t)(n0 + (tid >> 2)) * Kdim + k0 + ((tid & 3) << 4);
            __builtin_amdgcn_global_load_lds((const GAS void*)g, (LAS void*)ldsp, 16, 0, 0);
            __builtin_amdgcn_global_load_lds((const GAS void*)(g + (size_t)64 * Kdim),
                                             (LAS void*)(ldsp + 4096), 16, 0, 0);
        } else {
            const int row = tid >> 1, cb = (tid & 1) << 5;
            const int4* src = (const int4*)(W32 + (size_t)(n0 + row) * Kdim + k0 + cb);
            int t[8];
#pragma unroll
            for (int j = 0; j < 8; ++j) {
                int4 vv = src[j];
                t[j] = pack4i8(vv.x, vv.y, vv.z, vv.w);
            }
            int4* dst = (int4*)&Bs[buf][row * BK + cb];
            dst[0] = make_int4(t[0], t[1], t[2], t[3]);
            dst[1] = make_int4(t[4], t[5], t[6], t[7]);
        }
    };

    stage(0, 0);
    for (int kt = 0; kt < KT; ++kt) {
        const int cur = kt & 1;
        __syncthreads();
        if (kt + 1 < KT) stage(cur ^ 1, kt + 1);

        v4i a[4], b[4];
        const int koff = kgrp << 4;
#pragma unroll
        for (int i = 0; i < 4; ++i) {
            a[i] = *(const v4i*)&As[cur][(wm * 64 + i * 16 + lrow) * BK + koff];
            b[i] = *(const v4i*)&Bs[cur][(wn * 64 + i * 16 + lrow) * BK + koff];
        }
#pragma unroll
        for (int i = 0; i < 4; ++i)
#pragma unroll
            for (int j = 0; j < 4; ++j)
                acc[i][j] = __builtin_amdgcn_mfma_i32_16x16x64_i8(a[i], b[j], acc[i][j], 0, 0, 0);
    }

#pragma unroll
    for (int j = 0; j < 4; ++j) {
        const int col = n0 + wn * 64 + j * 16 + lrow;
        const float sc = ascale * wscale[col];
        const float bb = bias[col];
#pragma unroll
        for (int i = 0; i < 4; ++i) {
            const int r0 = m0 + wm * 64 + i * 16 + (kgrp << 2);
            float* o = out + (size_t)r0 * Ndim + col;
#pragma unroll
            for (int r = 0; r < 4; ++r)
                o[(size_t)r * Ndim] = (float)acc[i][j][r] * sc + bb;
        }
    }
}

extern "C" void kernel_launch(void* const* d_in, const int* in_sizes, int n_in,
                              void* d_out, int out_size, void* d_ws, size_t ws_size,
                              hipStream_t stream) {
    const float* x      = (const float*)d_in[0];
    const int*   w32    = (const int*)d_in[1];   // int8 values sign-extended to int32
    const float* wscale = (const float*)d_in[2];
    const float* asc    = (const float*)d_in[3];
    const float* bias   = (const float*)d_in[4];
    float* out = (float*)d_out;

    const size_t nx = (size_t)Mdim * Kdim;  // 33,554,432 B for x_int8
    const size_t nw = (size_t)Ndim * Kdim;  // 67,108,864 B for w_int8
    int8_t* xq = (int8_t*)d_ws;
    int8_t* wq = xq + nx;

    const bool haveX = ws_size >= nx;
    const bool haveW = ws_size >= nx + nw;

    if (haveW) {
        k_prep<<<NQB + NWB, 256, 0, stream>>>(x, w32, asc, xq, wq);
        dim3 grid((Mdim / 256) * (Ndim / 256));  // 2048
        k_gemm256<<<grid, 512, 0, stream>>>(xq, wq, wscale, asc, bias, out);
    } else if (haveX) {
        k_quant_x<<<NQB, 256, 0, stream>>>(x, asc, xq);
        dim3 grid((Mdim / 128) * (Ndim / 128));  // 8192
        k_gemm<true, false><<<grid, 256, 0, stream>>>(xq, x, wq, w32, wscale, asc, bias, out);
    } else {
        dim3 grid((Mdim / 128) * (Ndim / 128));
        k_gemm<false, false><<<grid, 256, 0, stream>>>(xq, x, wq, w32, wscale, asc, bias, out);
    }
}